// Round 3
// baseline (1407.146 us; speedup 1.0000x reference)
//
#include <hip/hip_runtime.h>
#include <stdint.h>

#define NFULL 1024
#define NHUB  512
#define NTOP  256
#define EFULL 523776
#define EHUB  130816
#define ETOP  32640
#define SLOPE 0.01f

// ea = leaky(edge_z[ef] @ W + b), written DIRECTLY into out[ef][col..col+64);
// also per-row mean -> w2[e] (branch-local index). All fp32.
__global__ void k_ea(const float* __restrict__ ez,
                     const int* __restrict__ mask,
                     const float* __restrict__ Wf,   // [64][64]
                     const float* __restrict__ bf,   // [64]
                     float* __restrict__ outp, int col,
                     float* __restrict__ w2, int E)
{
  int e = blockIdx.x * blockDim.x + threadIdx.x;
  if (e >= E) return;
  int ef = mask ? mask[e] : e;
  const float* row = ez + (size_t)ef * 64;
  float acc[64];
  #pragma unroll
  for (int j = 0; j < 64; j++) acc[j] = bf[j];
  #pragma unroll
  for (int k0 = 0; k0 < 64; k0 += 4){
    float4 a4 = *(const float4*)(row + k0);
    float av[4]; av[0]=a4.x; av[1]=a4.y; av[2]=a4.z; av[3]=a4.w;
    #pragma unroll
    for (int q = 0; q < 4; q++){
      float a = av[q];
      const float* wr = Wf + (k0 + q) * 64;
      #pragma unroll
      for (int j = 0; j < 64; j++) acc[j] += a * wr[j];
    }
  }
  float s = 0.f;
  #pragma unroll
  for (int j = 0; j < 64; j++){
    float v = acc[j];
    v = v >= 0.f ? v : SLOPE * v;
    acc[j] = v; s += v;
  }
  w2[e] = s * (1.0f / 64.0f);
  float* orow = outp + (size_t)ef * 192 + col;
  #pragma unroll
  for (int j0 = 0; j0 < 64; j0 += 4){
    float4 o; o.x = acc[j0]; o.y = acc[j0+1]; o.z = acc[j0+2]; o.w = acc[j0+3];
    *(float4*)(orow + j0) = o;
  }
}

// Dense adjacency: A[i][j]=A[j][i]=w2[e]; diag=1 (self loop). A pre-zeroed.
__global__ void k_scatterA(const int* __restrict__ src, const int* __restrict__ dst,
                           const float* __restrict__ w2, float* __restrict__ A,
                           int E, int n)
{
  int t = blockIdx.x * blockDim.x + threadIdx.x;
  if (t < E){
    int i = src[t], j = dst[t]; float v = w2[t];
    A[(size_t)i * n + j] = v;
    A[(size_t)j * n + i] = v;
  }
  if (t < n) A[(size_t)t * n + t] = 1.0f;
}

// deg[i] = rowsum(A); dinv = deg>0 ? rsqrt : 0
__global__ void k_deg(const float* __restrict__ A, float* __restrict__ dinv, int n)
{
  int i = blockIdx.x, l = threadIdx.x;
  float s = 0.f;
  for (int j = l; j < n; j += 64) s += A[(size_t)i * n + j];
  #pragma unroll
  for (int o = 32; o > 0; o >>= 1) s += __shfl_down(s, o);
  if (l == 0) dinv[i] = (s > 0.f) ? rsqrtf(s) : 0.f;
}

__global__ void k_norm(float* __restrict__ A, const float* __restrict__ dinv, int n)
{
  int t = blockIdx.x * blockDim.x + threadIdx.x;
  if (t >= n * n) return;
  int i = t / n, j = t - i * n;
  A[t] *= dinv[i] * dinv[j];
}

// h = concat(node_hidden[gidx], weather) @ gW   (bias added later)
__global__ void k_h(const float* __restrict__ nodez,
                    const float* __restrict__ wx,
                    const int* __restrict__ gidx,
                    const float* __restrict__ gW, // [144][gout]
                    float* __restrict__ h, int n, int gout)
{
  int t = blockIdx.x * blockDim.x + threadIdx.x;
  if (t >= n * gout) return;
  int i = t / gout, c = t - i * gout;
  const float* nr = nodez + (size_t)(gidx ? gidx[i] : i) * 128;
  float acc = 0.f;
  for (int k = 0; k < 128; k++) acc += nr[k] * gW[k * gout + c];
  const float* wr = wx + (size_t)i * 16;
  for (int k = 0; k < 16; k++) acc += wr[k] * gW[(128 + k) * gout + c];
  h[t] = acc;
}

// xh = leaky(A_norm @ h + b)
__global__ void k_xh(const float* __restrict__ A, const float* __restrict__ h,
                     const float* __restrict__ gb,
                     float* __restrict__ xh, int n, int gout)
{
  int i = blockIdx.x, c = threadIdx.x;
  float acc = 0.f;
  for (int j = 0; j < n; j++) acc += A[(size_t)i * n + j] * h[(size_t)j * gout + c];
  acc += gb[c];
  xh[(size_t)i * gout + c] = acc >= 0.f ? acc : SLOPE * acc;
}

// tri[e] = sigmoid(dot(xh[src], xh[dst]))
__global__ void k_tri(const float* __restrict__ xh, const int* __restrict__ sb,
                      const int* __restrict__ db, float* __restrict__ tri,
                      int E, int gout)
{
  int e = blockIdx.x * blockDim.x + threadIdx.x;
  if (e >= E) return;
  const float4* xi = (const float4*)(xh + (size_t)sb[e] * gout);
  const float4* xj = (const float4*)(xh + (size_t)db[e] * gout);
  float s = 0.f;
  for (int c = 0; c < gout / 4; c++){
    float4 a = xi[c], b = xj[c];
    s += a.x*b.x + a.y*b.y + a.z*b.z + a.w*b.w;
  }
  tri[e] = 1.f / (1.f + __expf(-s));
}

__global__ void k_inv(const int* __restrict__ mask, int* __restrict__ inv, int E)
{
  int e = blockIdx.x * blockDim.x + threadIdx.x;
  if (e < E) inv[mask[e]] = e;
}

// In-place: out[e][br*64+h] *= (1 + tri*cW[h] + cb[h]) if edge present, else 0.
// One float4 chunk per thread: 48 chunks per out row.
__global__ void k_final(const float* __restrict__ triT, const float* __restrict__ triH,
                        const float* __restrict__ triF,
                        const int* __restrict__ invT, const int* __restrict__ invH,
                        const float* __restrict__ cwT, const float* __restrict__ cbT,
                        const float* __restrict__ cwH, const float* __restrict__ cbH,
                        const float* __restrict__ cwF, const float* __restrict__ cbF,
                        float* out)
{
  __shared__ float cw[3][64], cb[3][64];
  int lt = threadIdx.x;
  if (lt < 64)       { cw[0][lt] = cwT[lt]; cb[0][lt] = cbT[lt]; }
  else if (lt < 128) { int l = lt - 64;  cw[1][l] = cwH[l]; cb[1][l] = cbH[l]; }
  else if (lt < 192) { int l = lt - 128; cw[2][l] = cwF[l]; cb[2][l] = cbF[l]; }
  __syncthreads();
  int t = blockIdx.x * 256 + threadIdx.x;
  const int TOT = EFULL * 48;
  if (t >= TOT) return;
  int e = t / 48;
  int c = t - e * 48;
  int br = c >> 4, h0 = (c & 15) * 4;
  int eb; const float* tri;
  if (br == 0)      { eb = invT[e]; tri = triT; }
  else if (br == 1) { eb = invH[e]; tri = triH; }
  else              { eb = e;       tri = triF; }
  float* p = out + (size_t)e * 192 + br * 64 + h0;
  if (eb >= 0){
    float tv = tri[eb];
    float4 v = *(const float4*)p;
    float4 o;
    o.x = v.x * (1.f + tv * cw[br][h0+0] + cb[br][h0+0]);
    o.y = v.y * (1.f + tv * cw[br][h0+1] + cb[br][h0+1]);
    o.z = v.z * (1.f + tv * cw[br][h0+2] + cb[br][h0+2]);
    o.w = v.w * (1.f + tv * cw[br][h0+3] + cb[br][h0+3]);
    *(float4*)p = o;
  } else {
    float4 z; z.x = 0.f; z.y = 0.f; z.z = 0.f; z.w = 0.f;
    *(float4*)p = z;
  }
}

extern "C" void kernel_launch(void* const* d_in, const int* in_sizes, int n_in,
                              void* d_out, int out_size, void* d_ws, size_t ws_size,
                              hipStream_t stream)
{
  const float* nodez  = (const float*)d_in[0];
  const float* wx     = (const float*)d_in[1];
  const float* hub_wx = (const float*)d_in[2];
  const float* top_wx = (const float*)d_in[3];
  const float* ez     = (const float*)d_in[4];
  const int* adj   = (const int*)d_in[5];
  const int* hadj  = (const int*)d_in[6];
  const int* tadj  = (const int*)d_in[7];
  const int* hidx  = (const int*)d_in[8];
  const int* tidx  = (const int*)d_in[9];
  const int* hmask = (const int*)d_in[13];
  const int* tmask = (const int*)d_in[14];
  const float* dgW_t = (const float*)d_in[15];
  const float* dgb_t = (const float*)d_in[16];
  const float* gW_t  = (const float*)d_in[17];
  const float* gb_t  = (const float*)d_in[18];
  const float* cW_t  = (const float*)d_in[19];
  const float* cb_t  = (const float*)d_in[20];
  const float* dgW_h = (const float*)d_in[21];
  const float* dgb_h = (const float*)d_in[22];
  const float* gW_h  = (const float*)d_in[23];
  const float* gb_h  = (const float*)d_in[24];
  const float* cW_h  = (const float*)d_in[25];
  const float* cb_h  = (const float*)d_in[26];
  const float* dgW_f = (const float*)d_in[27];
  const float* dgb_f = (const float*)d_in[28];
  const float* gW_f  = (const float*)d_in[29];
  const float* gb_f  = (const float*)d_in[30];
  const float* cW_f  = (const float*)d_in[31];
  const float* cb_f  = (const float*)d_in[32];

  char* w = (char*)d_ws;
  size_t off = 0;
  auto alloc = [&](size_t bytes) -> char* {
    char* p = w + off;
    off += (bytes + 255) & ~(size_t)255;
    return p;
  };
  // ~14 MB total
  float* triT = (float*)alloc((size_t)ETOP  * 4);
  float* triH = (float*)alloc((size_t)EHUB  * 4);
  float* triF = (float*)alloc((size_t)EFULL * 4);
  float* w2   = (float*)alloc((size_t)EFULL * 4);
  float* A    = (float*)alloc((size_t)NFULL * NFULL * 4);
  float* dinv = (float*)alloc((size_t)NFULL * 4);
  float* hbuf = (float*)alloc((size_t)NFULL * 128 * 4);
  float* xh   = (float*)alloc((size_t)NFULL * 128 * 4);
  int* invT   = (int*)alloc((size_t)EFULL * 4);
  int* invH   = (int*)alloc((size_t)EFULL * 4);
  (void)ws_size; (void)in_sizes; (void)n_in; (void)out_size;

  float* outp = (float*)d_out;

  hipMemsetAsync(invT, 0xFF, (size_t)EFULL * 4, stream);
  hipMemsetAsync(invH, 0xFF, (size_t)EFULL * 4, stream);
  k_inv<<<(ETOP + 255) / 256, 256, 0, stream>>>(tmask, invT, ETOP);
  k_inv<<<(EHUB + 255) / 256, 256, 0, stream>>>(hmask, invH, EHUB);

  struct Br {
    int bi, E, n, gout;
    const int *adjb, *maskb, *gidx;
    const float *wxb, *dgW, *dgb, *gW, *gb;
    float* triB;
  };
  Br brs[3] = {
    {0, ETOP,  NTOP,  128, tadj, tmask,   tidx,    top_wx, dgW_t, dgb_t, gW_t, gb_t, triT},
    {1, EHUB,  NHUB,  64,  hadj, hmask,   hidx,    hub_wx, dgW_h, dgb_h, gW_h, gb_h, triH},
    {2, EFULL, NFULL, 64,  adj,  nullptr, nullptr, wx,     dgW_f, dgb_f, gW_f, gb_f, triF},
  };
  for (int b = 0; b < 3; b++){
    Br& B = brs[b];
    const int* sb = B.adjb;
    const int* db = B.adjb + B.E;
    k_ea<<<(B.E + 255) / 256, 256, 0, stream>>>(ez, B.maskb, B.dgW, B.dgb,
                                                outp, B.bi * 64, w2, B.E);
    hipMemsetAsync(A, 0, (size_t)B.n * B.n * 4, stream);
    k_scatterA<<<(B.E + 255) / 256, 256, 0, stream>>>(sb, db, w2, A, B.E, B.n);
    k_deg<<<B.n, 64, 0, stream>>>(A, dinv, B.n);
    k_norm<<<(B.n * B.n + 255) / 256, 256, 0, stream>>>(A, dinv, B.n);
    k_h<<<(B.n * B.gout + 255) / 256, 256, 0, stream>>>(nodez, B.wxb, B.gidx, B.gW, hbuf, B.n, B.gout);
    k_xh<<<B.n, B.gout, 0, stream>>>(A, hbuf, B.gb, xh, B.n, B.gout);
    k_tri<<<(B.E + 255) / 256, 256, 0, stream>>>(xh, sb, db, B.triB, B.E, B.gout);
  }

  k_final<<<(EFULL * 48 + 255) / 256, 256, 0, stream>>>(
      triT, triH, triF, invT, invH,
      cW_t, cb_t, cW_h, cb_h, cW_f, cb_f,
      outp);
}

// Round 4
// 1239.112 us; speedup vs baseline: 1.1356x; 1.1356x over previous
//
#include <hip/hip_runtime.h>
#include <stdint.h>

#define NFULL 1024
#define NHUB  512
#define NTOP  256
#define EFULL 523776
#define EHUB  130816
#define ETOP  32640
#define ETOT  (ETOP + EHUB + EFULL)   // 687232
#define NTOT  (NTOP + NHUB + NFULL)   // 1792
// h/xh row-buffer offsets (floats): top 256*128, hub 512*64, full 1024*64
#define HOFF_H 32768
#define HOFF_F 65536
#define HTOT   131072
#define SLOPE 0.01f

__device__ __forceinline__ int trioff(int i, int n){ return (i * (2 * n - i - 1)) >> 1; }

// invT[e]=-1, invH[e]=-1 for all full edges
__global__ void k_init(int* __restrict__ invT, int* __restrict__ invH)
{
  int t = blockIdx.x * 256 + threadIdx.x;
  if (t < EFULL){ invT[t] = -1; invH[t] = -1; }
}

// scatter branch-local ids into full-edge-indexed inverse maps
__global__ void k_inv(const int* __restrict__ tmask, const int* __restrict__ hmask,
                      int* __restrict__ invT, int* __restrict__ invH)
{
  int t = blockIdx.x * 256 + threadIdx.x;
  if (t < ETOP) invT[tmask[t]] = t;
  else if (t < ETOP + EHUB) invH[hmask[t - ETOP]] = t - ETOP;
}

// ea = leaky(edge_z[ef] @ W + b) -> out[ef][col..col+64); mean -> w2_all[t]
__global__ void k_ea_all(const float* __restrict__ ez,
                         const int* __restrict__ tmask, const int* __restrict__ hmask,
                         const float* __restrict__ Wt, const float* __restrict__ bt,
                         const float* __restrict__ Wh, const float* __restrict__ bh,
                         const float* __restrict__ Wf, const float* __restrict__ bf,
                         float* __restrict__ outp, float* __restrict__ w2_all)
{
  int t = blockIdx.x * blockDim.x + threadIdx.x;
  if (t >= ETOT) return;
  int ef, col;
  const float* W; const float* bb;
  if (t < ETOP)             { ef = tmask[t];         col = 0;   W = Wt; bb = bt; }
  else if (t < ETOP + EHUB) { ef = hmask[t - ETOP];  col = 64;  W = Wh; bb = bh; }
  else                      { ef = t - ETOP - EHUB;  col = 128; W = Wf; bb = bf; }

  const float* row = ez + (size_t)ef * 64;
  float acc[64];
  #pragma unroll
  for (int j = 0; j < 64; j++) acc[j] = bb[j];
  #pragma unroll
  for (int k0 = 0; k0 < 64; k0 += 4){
    float4 a4 = *(const float4*)(row + k0);
    float av[4]; av[0]=a4.x; av[1]=a4.y; av[2]=a4.z; av[3]=a4.w;
    #pragma unroll
    for (int q = 0; q < 4; q++){
      float a = av[q];
      const float* wr = W + (k0 + q) * 64;
      #pragma unroll
      for (int j = 0; j < 64; j++) acc[j] += a * wr[j];
    }
  }
  float s = 0.f;
  #pragma unroll
  for (int j = 0; j < 64; j++){
    float v = acc[j];
    v = v >= 0.f ? v : SLOPE * v;
    acc[j] = v; s += v;
  }
  w2_all[t] = s * (1.0f / 64.0f);
  float* orow = outp + (size_t)ef * 192 + col;
  #pragma unroll
  for (int j0 = 0; j0 < 64; j0 += 4){
    float4 o; o.x = acc[j0]; o.y = acc[j0+1]; o.z = acc[j0+2]; o.w = acc[j0+3];
    *(float4*)(orow + j0) = o;
  }
}

// deg[i] = 1 + sum_j!=i w2[e(i,j)] via closed-form edge ids; dinv = deg>0 ? rsqrt : 0
__global__ void k_deg_all(const float* __restrict__ w2_all, float* __restrict__ dinv_all)
{
  int b = blockIdx.x, l = threadIdx.x;
  int n, i, boff; const float* w2;
  if (b < NTOP)             { n = NTOP;  i = b;               boff = 0;           w2 = w2_all; }
  else if (b < NTOP + NHUB) { n = NHUB;  i = b - NTOP;        boff = NTOP;        w2 = w2_all + ETOP; }
  else                      { n = NFULL; i = b - NTOP - NHUB; boff = NTOP + NHUB; w2 = w2_all + ETOP + EHUB; }
  float s = 0.f;
  for (int j = l; j < n; j += 64){
    if (j == i) continue;
    int e = (j < i) ? (trioff(j, n) + i - j - 1) : (trioff(i, n) + j - i - 1);
    s += w2[e];
  }
  #pragma unroll
  for (int o = 32; o > 0; o >>= 1) s += __shfl_down(s, o);
  if (l == 0){
    float deg = s + 1.0f;
    dinv_all[boff + i] = (deg > 0.f) ? rsqrtf(deg) : 0.f;
  }
}

// h = concat(node_hidden[gidx], weather) @ gW  (no bias)
__global__ void k_h_all(const float* __restrict__ nodez,
                        const float* __restrict__ wx, const float* __restrict__ hwx,
                        const float* __restrict__ twx,
                        const int* __restrict__ hidx, const int* __restrict__ tidx,
                        const float* __restrict__ gWt, const float* __restrict__ gWh,
                        const float* __restrict__ gWf,
                        float* __restrict__ h_all)
{
  int t = blockIdx.x * 256 + threadIdx.x;
  if (t >= HTOT) return;
  int i, c, gout, nrow; const float* gW; const float* wxp; const int* gidx; float* hp;
  if (t < HOFF_H)      { gout = 128; i = t / 128;  c = t & 127; gW = gWt; wxp = twx; gidx = tidx; hp = h_all; }
  else if (t < HOFF_F) { int u = t - HOFF_H; gout = 64; i = u / 64; c = u & 63; gW = gWh; wxp = hwx; gidx = hidx; hp = h_all + HOFF_H; }
  else                 { int u = t - HOFF_F; gout = 64; i = u / 64; c = u & 63; gW = gWf; wxp = wx;  gidx = nullptr; hp = h_all + HOFF_F; }
  nrow = gidx ? gidx[i] : i;
  const float* nr = nodez + (size_t)nrow * 128;
  float acc = 0.f;
  for (int k = 0; k < 128; k++) acc += nr[k] * gW[k * gout + c];
  const float* wr = wxp + (size_t)i * 16;
  for (int k = 0; k < 16; k++) acc += wr[k] * gW[(128 + k) * gout + c];
  hp[(size_t)i * gout + c] = acc;
}

// xh[i][c] = leaky( dinv[i] * sum_j coef(i,j)*dinv[j]*h[j][c] + b[c] ), A built on the fly
__global__ void k_xh_all(const float* __restrict__ w2_all, const float* __restrict__ dinv_all,
                         const float* __restrict__ h_all,
                         const float* __restrict__ gbt, const float* __restrict__ gbh,
                         const float* __restrict__ gbf,
                         float* __restrict__ xh_all)
{
  __shared__ float part[256];
  int b = blockIdx.x, tid = threadIdx.x;
  int n, i, gout; const float* w2; const float* dinv; const float* hb; const float* gb; float* xb;
  if (b < NTOP){
    n = NTOP; i = b; gout = 128;
    w2 = w2_all; dinv = dinv_all; hb = h_all; gb = gbt; xb = xh_all;
  } else if (b < NTOP + NHUB){
    n = NHUB; i = b - NTOP; gout = 64;
    w2 = w2_all + ETOP; dinv = dinv_all + NTOP; hb = h_all + HOFF_H; gb = gbh; xb = xh_all + HOFF_H;
  } else {
    n = NFULL; i = b - NTOP - NHUB; gout = 64;
    w2 = w2_all + ETOP + EHUB; dinv = dinv_all + NTOP + NHUB; hb = h_all + HOFF_F; gb = gbf; xb = xh_all + HOFF_F;
  }
  int SJ = 256 / gout;            // 2 or 4 j-stripes
  int c = tid & (gout - 1);
  int js = tid / gout;
  float acc = 0.f;
  for (int j = js; j < n; j += SJ){
    float coef;
    if (j == i) coef = 1.0f;
    else {
      int e = (j < i) ? (trioff(j, n) + i - j - 1) : (trioff(i, n) + j - i - 1);
      coef = w2[e];
    }
    coef *= dinv[j];
    acc += coef * hb[(size_t)j * gout + c];
  }
  part[tid] = acc;
  __syncthreads();
  if (js == 0){
    float s = acc;
    for (int q = 1; q < SJ; q++) s += part[q * gout + c];
    s = dinv[i] * s + gb[c];
    xb[(size_t)i * gout + c] = s >= 0.f ? s : SLOPE * s;
  }
}

// tri[t] = sigmoid(dot(xh[src], xh[dst]))
__global__ void k_tri_all(const float* __restrict__ xh_all,
                          const int* __restrict__ tadj, const int* __restrict__ hadj,
                          const int* __restrict__ fadj,
                          float* __restrict__ tri_all)
{
  int t = blockIdx.x * blockDim.x + threadIdx.x;
  if (t >= ETOT) return;
  int e, gout, E; const int* adjb; const float* xb;
  if (t < ETOP)             { e = t;               E = ETOP;  gout = 128; adjb = tadj; xb = xh_all; }
  else if (t < ETOP + EHUB) { e = t - ETOP;        E = EHUB;  gout = 64;  adjb = hadj; xb = xh_all + HOFF_H; }
  else                      { e = t - ETOP - EHUB; E = EFULL; gout = 64;  adjb = fadj; xb = xh_all + HOFF_F; }
  int si = adjb[e], di = adjb[E + e];
  const float4* xi = (const float4*)(xb + (size_t)si * gout);
  const float4* xj = (const float4*)(xb + (size_t)di * gout);
  float s = 0.f;
  for (int c = 0; c < gout / 4; c++){
    float4 a = xi[c], bb = xj[c];
    s += a.x*bb.x + a.y*bb.y + a.z*bb.z + a.w*bb.w;
  }
  tri_all[t] = 1.f / (1.f + __expf(-s));
}

// In-place: out[e][br*64+h] *= (1 + tri*cW[h] + cb[h]) if present, else 0.
__global__ void k_final(const float* __restrict__ tri_all,
                        const int* __restrict__ invT, const int* __restrict__ invH,
                        const float* __restrict__ cwT, const float* __restrict__ cbT,
                        const float* __restrict__ cwH, const float* __restrict__ cbH,
                        const float* __restrict__ cwF, const float* __restrict__ cbF,
                        float* out)
{
  __shared__ float cw[3][64], cb[3][64];
  int lt = threadIdx.x;
  if (lt < 64)       { cw[0][lt] = cwT[lt]; cb[0][lt] = cbT[lt]; }
  else if (lt < 128) { int l = lt - 64;  cw[1][l] = cwH[l]; cb[1][l] = cbH[l]; }
  else if (lt < 192) { int l = lt - 128; cw[2][l] = cwF[l]; cb[2][l] = cbF[l]; }
  __syncthreads();
  int t = blockIdx.x * 256 + threadIdx.x;
  const int TOT = EFULL * 48;
  if (t >= TOT) return;
  int e = t / 48;
  int c = t - e * 48;
  int br = c >> 4, h0 = (c & 15) * 4;
  int eb; const float* tri;
  if (br == 0)      { eb = invT[e]; tri = tri_all; }
  else if (br == 1) { eb = invH[e]; tri = tri_all + ETOP; }
  else              { eb = e;       tri = tri_all + ETOP + EHUB; }
  float* p = out + (size_t)e * 192 + br * 64 + h0;
  if (eb >= 0){
    float tv = tri[eb];
    float4 v = *(const float4*)p;
    float4 o;
    o.x = v.x * (1.f + tv * cw[br][h0+0] + cb[br][h0+0]);
    o.y = v.y * (1.f + tv * cw[br][h0+1] + cb[br][h0+1]);
    o.z = v.z * (1.f + tv * cw[br][h0+2] + cb[br][h0+2]);
    o.w = v.w * (1.f + tv * cw[br][h0+3] + cb[br][h0+3]);
    *(float4*)p = o;
  } else {
    float4 z; z.x = 0.f; z.y = 0.f; z.z = 0.f; z.w = 0.f;
    *(float4*)p = z;
  }
}

extern "C" void kernel_launch(void* const* d_in, const int* in_sizes, int n_in,
                              void* d_out, int out_size, void* d_ws, size_t ws_size,
                              hipStream_t stream)
{
  const float* nodez  = (const float*)d_in[0];
  const float* wx     = (const float*)d_in[1];
  const float* hub_wx = (const float*)d_in[2];
  const float* top_wx = (const float*)d_in[3];
  const float* ez     = (const float*)d_in[4];
  const int* adj   = (const int*)d_in[5];
  const int* hadj  = (const int*)d_in[6];
  const int* tadj  = (const int*)d_in[7];
  const int* hidx  = (const int*)d_in[8];
  const int* tidx  = (const int*)d_in[9];
  const int* hmask = (const int*)d_in[13];
  const int* tmask = (const int*)d_in[14];
  const float* dgW_t = (const float*)d_in[15];
  const float* dgb_t = (const float*)d_in[16];
  const float* gW_t  = (const float*)d_in[17];
  const float* gb_t  = (const float*)d_in[18];
  const float* cW_t  = (const float*)d_in[19];
  const float* cb_t  = (const float*)d_in[20];
  const float* dgW_h = (const float*)d_in[21];
  const float* dgb_h = (const float*)d_in[22];
  const float* gW_h  = (const float*)d_in[23];
  const float* gb_h  = (const float*)d_in[24];
  const float* cW_h  = (const float*)d_in[25];
  const float* cb_h  = (const float*)d_in[26];
  const float* dgW_f = (const float*)d_in[27];
  const float* dgb_f = (const float*)d_in[28];
  const float* gW_f  = (const float*)d_in[29];
  const float* gb_f  = (const float*)d_in[30];
  const float* cW_f  = (const float*)d_in[31];
  const float* cb_f  = (const float*)d_in[32];

  char* w = (char*)d_ws;
  size_t off = 0;
  auto alloc = [&](size_t bytes) -> char* {
    char* p = w + off;
    off += (bytes + 255) & ~(size_t)255;
    return p;
  };
  float* w2_all   = (float*)alloc((size_t)ETOT * 4);
  float* tri_all  = (float*)alloc((size_t)ETOT * 4);
  float* dinv_all = (float*)alloc((size_t)NTOT * 4);
  float* h_all    = (float*)alloc((size_t)HTOT * 4);
  float* xh_all   = (float*)alloc((size_t)HTOT * 4);
  int* invT       = (int*)alloc((size_t)EFULL * 4);
  int* invH       = (int*)alloc((size_t)EFULL * 4);
  (void)ws_size; (void)in_sizes; (void)n_in; (void)out_size;

  float* outp = (float*)d_out;

  k_init<<<(EFULL + 255) / 256, 256, 0, stream>>>(invT, invH);
  k_inv<<<(ETOP + EHUB + 255) / 256, 256, 0, stream>>>(tmask, hmask, invT, invH);
  k_ea_all<<<(ETOT + 255) / 256, 256, 0, stream>>>(ez, tmask, hmask,
      dgW_t, dgb_t, dgW_h, dgb_h, dgW_f, dgb_f, outp, w2_all);
  k_h_all<<<(HTOT + 255) / 256, 256, 0, stream>>>(nodez, wx, hub_wx, top_wx,
      hidx, tidx, gW_t, gW_h, gW_f, h_all);
  k_deg_all<<<NTOT, 64, 0, stream>>>(w2_all, dinv_all);
  k_xh_all<<<NTOT, 256, 0, stream>>>(w2_all, dinv_all, h_all, gb_t, gb_h, gb_f, xh_all);
  k_tri_all<<<(ETOT + 255) / 256, 256, 0, stream>>>(xh_all, tadj, hadj, adj, tri_all);
  k_final<<<(EFULL * 48 + 255) / 256, 256, 0, stream>>>(
      tri_all, invT, invH, cW_t, cb_t, cW_h, cb_h, cW_f, cb_f, outp);
}

// Round 5
// 934.923 us; speedup vs baseline: 1.5051x; 1.3254x over previous
//
#include <hip/hip_runtime.h>
#include <stdint.h>

#define NFULL 1024
#define NHUB  512
#define NTOP  256
#define EFULL 523776
#define EHUB  130816
#define ETOP  32640
#define ETOT  (ETOP + EHUB + EFULL)   // 687232
#define NTOT  (NTOP + NHUB + NFULL)   // 1792
// h/xh row-buffer offsets (floats): top 256*128, hub 512*64, full 1024*64
#define HOFF_H 32768
#define HOFF_F 65536
#define HTOT   131072
#define SLOPE 0.01f

// per-branch block ranges for k_ea_all (256 edges/block)
#define NB_T 128    // ceil(32640/256)
#define NB_H 511    // 130816/256 exact
#define NB_F 2046   // 523776/256 exact

__device__ __forceinline__ int trioff(int i, int n){ return (i * (2 * n - i - 1)) >> 1; }

// invT[e]=-1, invH[e]=-1 for all full edges
__global__ void k_init(int* __restrict__ invT, int* __restrict__ invH)
{
  int t = blockIdx.x * 256 + threadIdx.x;
  if (t < EFULL){ invT[t] = -1; invH[t] = -1; }
}

// scatter branch-local ids into full-edge-indexed inverse maps
__global__ void k_inv(const int* __restrict__ tmask, const int* __restrict__ hmask,
                      int* __restrict__ invT, int* __restrict__ invH)
{
  int t = blockIdx.x * 256 + threadIdx.x;
  if (t < ETOP) invT[tmask[t]] = t;
  else if (t < ETOP + EHUB) invH[hmask[t - ETOP]] = t - ETOP;
}

// ea = leaky(edge_z[ef] @ W + b) -> out[ef][col..col+64); mean -> w2_all.
// Branch-uniform blocks; W staged in LDS (broadcast reads); acc[64] in VGPRs
// (__launch_bounds__(256,2) caps at 256 VGPRs -> no scratch spill).
__global__ __launch_bounds__(256, 2)
void k_ea_all(const float* __restrict__ ez,
              const int* __restrict__ tmask, const int* __restrict__ hmask,
              const float* __restrict__ Wt, const float* __restrict__ bt,
              const float* __restrict__ Wh, const float* __restrict__ bh,
              const float* __restrict__ Wf, const float* __restrict__ bf,
              float* __restrict__ outp, float* __restrict__ w2_all)
{
  __shared__ float sW[4096];
  __shared__ float sB[64];
  int b = blockIdx.x, tid = threadIdx.x;
  int bloc, E, w2off, col; const int* mask; const float* W; const float* bb;
  if (b < NB_T)             { bloc = b;               E = ETOP;  w2off = 0;           col = 0;   mask = tmask;   W = Wt; bb = bt; }
  else if (b < NB_T + NB_H) { bloc = b - NB_T;        E = EHUB;  w2off = ETOP;        col = 64;  mask = hmask;   W = Wh; bb = bh; }
  else                      { bloc = b - NB_T - NB_H; E = EFULL; w2off = ETOP + EHUB; col = 128; mask = nullptr; W = Wf; bb = bf; }
  {
    const float4* Wv = (const float4*)W;
    float4* sWv = (float4*)sW;
    #pragma unroll
    for (int q = 0; q < 4; q++) sWv[q * 256 + tid] = Wv[q * 256 + tid];
    if (tid < 64) sB[tid] = bb[tid];
  }
  __syncthreads();
  int t = bloc * 256 + tid;
  if (t >= E) return;
  int ef = mask ? mask[t] : t;
  const float* row = ez + (size_t)ef * 64;

  float acc[64];
  #pragma unroll
  for (int j = 0; j < 64; j++) acc[j] = sB[j];
  #pragma unroll
  for (int k0 = 0; k0 < 64; k0 += 4){
    float4 a4 = *(const float4*)(row + k0);
    float av[4]; av[0]=a4.x; av[1]=a4.y; av[2]=a4.z; av[3]=a4.w;
    #pragma unroll
    for (int q = 0; q < 4; q++){
      float a = av[q];
      const float* wr = sW + (k0 + q) * 64;
      #pragma unroll
      for (int j0 = 0; j0 < 64; j0 += 4){
        float4 w4 = *(const float4*)(wr + j0);
        acc[j0+0] += a * w4.x;
        acc[j0+1] += a * w4.y;
        acc[j0+2] += a * w4.z;
        acc[j0+3] += a * w4.w;
      }
    }
  }
  float s = 0.f;
  #pragma unroll
  for (int j = 0; j < 64; j++){
    float v = acc[j];
    v = v >= 0.f ? v : SLOPE * v;
    acc[j] = v; s += v;
  }
  w2_all[w2off + t] = s * (1.0f / 64.0f);
  float* orow = outp + (size_t)ef * 192 + col;
  #pragma unroll
  for (int j0 = 0; j0 < 64; j0 += 4){
    float4 o; o.x = acc[j0]; o.y = acc[j0+1]; o.z = acc[j0+2]; o.w = acc[j0+3];
    *(float4*)(orow + j0) = o;
  }
}

// deg[i] = 1 + sum_j!=i w2[e(i,j)] via closed-form edge ids; dinv = rsqrt(deg)
__global__ void k_deg_all(const float* __restrict__ w2_all, float* __restrict__ dinv_all)
{
  int b = blockIdx.x, l = threadIdx.x;
  int n, i, boff; const float* w2;
  if (b < NTOP)             { n = NTOP;  i = b;               boff = 0;           w2 = w2_all; }
  else if (b < NTOP + NHUB) { n = NHUB;  i = b - NTOP;        boff = NTOP;        w2 = w2_all + ETOP; }
  else                      { n = NFULL; i = b - NTOP - NHUB; boff = NTOP + NHUB; w2 = w2_all + ETOP + EHUB; }
  float s = 0.f;
  for (int j = l; j < n; j += 64){
    if (j == i) continue;
    int e = (j < i) ? (trioff(j, n) + i - j - 1) : (trioff(i, n) + j - i - 1);
    s += w2[e];
  }
  #pragma unroll
  for (int o = 32; o > 0; o >>= 1) s += __shfl_down(s, o);
  if (l == 0){
    float deg = s + 1.0f;
    dinv_all[boff + i] = (deg > 0.f) ? rsqrtf(deg) : 0.f;
  }
}

// h = concat(node_hidden[gidx], weather) @ gW  (no bias)
__global__ void k_h_all(const float* __restrict__ nodez,
                        const float* __restrict__ wx, const float* __restrict__ hwx,
                        const float* __restrict__ twx,
                        const int* __restrict__ hidx, const int* __restrict__ tidx,
                        const float* __restrict__ gWt, const float* __restrict__ gWh,
                        const float* __restrict__ gWf,
                        float* __restrict__ h_all)
{
  int t = blockIdx.x * 256 + threadIdx.x;
  if (t >= HTOT) return;
  int i, c, gout, nrow; const float* gW; const float* wxp; const int* gidx; float* hp;
  if (t < HOFF_H)      { gout = 128; i = t / 128;  c = t & 127; gW = gWt; wxp = twx; gidx = tidx; hp = h_all; }
  else if (t < HOFF_F) { int u = t - HOFF_H; gout = 64; i = u / 64; c = u & 63; gW = gWh; wxp = hwx; gidx = hidx; hp = h_all + HOFF_H; }
  else                 { int u = t - HOFF_F; gout = 64; i = u / 64; c = u & 63; gW = gWf; wxp = wx;  gidx = nullptr; hp = h_all + HOFF_F; }
  nrow = gidx ? gidx[i] : i;
  const float* nr = nodez + (size_t)nrow * 128;
  float acc = 0.f;
  for (int k = 0; k < 128; k++) acc += nr[k] * gW[k * gout + c];
  const float* wr = wxp + (size_t)i * 16;
  for (int k = 0; k < 16; k++) acc += wr[k] * gW[(128 + k) * gout + c];
  hp[(size_t)i * gout + c] = acc;
}

// xh[i][c] = leaky( dinv[i] * sum_j coef(i,j)*dinv[j]*h[j][c] + b[c] )
__global__ void k_xh_all(const float* __restrict__ w2_all, const float* __restrict__ dinv_all,
                         const float* __restrict__ h_all,
                         const float* __restrict__ gbt, const float* __restrict__ gbh,
                         const float* __restrict__ gbf,
                         float* __restrict__ xh_all)
{
  __shared__ float part[256];
  int b = blockIdx.x, tid = threadIdx.x;
  int n, i, gout; const float* w2; const float* dinv; const float* hb; const float* gb; float* xb;
  if (b < NTOP){
    n = NTOP; i = b; gout = 128;
    w2 = w2_all; dinv = dinv_all; hb = h_all; gb = gbt; xb = xh_all;
  } else if (b < NTOP + NHUB){
    n = NHUB; i = b - NTOP; gout = 64;
    w2 = w2_all + ETOP; dinv = dinv_all + NTOP; hb = h_all + HOFF_H; gb = gbh; xb = xh_all + HOFF_H;
  } else {
    n = NFULL; i = b - NTOP - NHUB; gout = 64;
    w2 = w2_all + ETOP + EHUB; dinv = dinv_all + NTOP + NHUB; hb = h_all + HOFF_F; gb = gbf; xb = xh_all + HOFF_F;
  }
  int SJ = 256 / gout;
  int c = tid & (gout - 1);
  int js = tid / gout;
  float acc = 0.f;
  for (int j = js; j < n; j += SJ){
    float coef;
    if (j == i) coef = 1.0f;
    else {
      int e = (j < i) ? (trioff(j, n) + i - j - 1) : (trioff(i, n) + j - i - 1);
      coef = w2[e];
    }
    coef *= dinv[j];
    acc += coef * hb[(size_t)j * gout + c];
  }
  part[tid] = acc;
  __syncthreads();
  if (js == 0){
    float s = acc;
    for (int q = 1; q < SJ; q++) s += part[q * gout + c];
    s = dinv[i] * s + gb[c];
    xb[(size_t)i * gout + c] = s >= 0.f ? s : SLOPE * s;
  }
}

// tri[t] = sigmoid(dot(xh[src], xh[dst]))
__global__ void k_tri_all(const float* __restrict__ xh_all,
                          const int* __restrict__ tadj, const int* __restrict__ hadj,
                          const int* __restrict__ fadj,
                          float* __restrict__ tri_all)
{
  int t = blockIdx.x * blockDim.x + threadIdx.x;
  if (t >= ETOT) return;
  int e, gout, E; const int* adjb; const float* xb;
  if (t < ETOP)             { e = t;               E = ETOP;  gout = 128; adjb = tadj; xb = xh_all; }
  else if (t < ETOP + EHUB) { e = t - ETOP;        E = EHUB;  gout = 64;  adjb = hadj; xb = xh_all + HOFF_H; }
  else                      { e = t - ETOP - EHUB; E = EFULL; gout = 64;  adjb = fadj; xb = xh_all + HOFF_F; }
  int si = adjb[e], di = adjb[E + e];
  const float4* xi = (const float4*)(xb + (size_t)si * gout);
  const float4* xj = (const float4*)(xb + (size_t)di * gout);
  float s = 0.f;
  for (int c = 0; c < gout / 4; c++){
    float4 a = xi[c], bb = xj[c];
    s += a.x*bb.x + a.y*bb.y + a.z*bb.z + a.w*bb.w;
  }
  tri_all[t] = 1.f / (1.f + __expf(-s));
}

// In-place: out[e][br*64+h] *= (1 + tri*cW[h] + cb[h]) if present, else 0.
__global__ void k_final(const float* __restrict__ tri_all,
                        const int* __restrict__ invT, const int* __restrict__ invH,
                        const float* __restrict__ cwT, const float* __restrict__ cbT,
                        const float* __restrict__ cwH, const float* __restrict__ cbH,
                        const float* __restrict__ cwF, const float* __restrict__ cbF,
                        float* out)
{
  __shared__ float cw[3][64], cb[3][64];
  int lt = threadIdx.x;
  if (lt < 64)       { cw[0][lt] = cwT[lt]; cb[0][lt] = cbT[lt]; }
  else if (lt < 128) { int l = lt - 64;  cw[1][l] = cwH[l]; cb[1][l] = cbH[l]; }
  else if (lt < 192) { int l = lt - 128; cw[2][l] = cwF[l]; cb[2][l] = cbF[l]; }
  __syncthreads();
  int t = blockIdx.x * 256 + threadIdx.x;
  const int TOT = EFULL * 48;
  if (t >= TOT) return;
  int e = t / 48;
  int c = t - e * 48;
  int br = c >> 4, h0 = (c & 15) * 4;
  int eb; const float* tri;
  if (br == 0)      { eb = invT[e]; tri = tri_all; }
  else if (br == 1) { eb = invH[e]; tri = tri_all + ETOP; }
  else              { eb = e;       tri = tri_all + ETOP + EHUB; }
  float* p = out + (size_t)e * 192 + br * 64 + h0;
  if (eb >= 0){
    float tv = tri[eb];
    float4 v = *(const float4*)p;
    float4 o;
    o.x = v.x * (1.f + tv * cw[br][h0+0] + cb[br][h0+0]);
    o.y = v.y * (1.f + tv * cw[br][h0+1] + cb[br][h0+1]);
    o.z = v.z * (1.f + tv * cw[br][h0+2] + cb[br][h0+2]);
    o.w = v.w * (1.f + tv * cw[br][h0+3] + cb[br][h0+3]);
    *(float4*)p = o;
  } else {
    float4 z; z.x = 0.f; z.y = 0.f; z.z = 0.f; z.w = 0.f;
    *(float4*)p = z;
  }
}

extern "C" void kernel_launch(void* const* d_in, const int* in_sizes, int n_in,
                              void* d_out, int out_size, void* d_ws, size_t ws_size,
                              hipStream_t stream)
{
  const float* nodez  = (const float*)d_in[0];
  const float* wx     = (const float*)d_in[1];
  const float* hub_wx = (const float*)d_in[2];
  const float* top_wx = (const float*)d_in[3];
  const float* ez     = (const float*)d_in[4];
  const int* adj   = (const int*)d_in[5];
  const int* hadj  = (const int*)d_in[6];
  const int* tadj  = (const int*)d_in[7];
  const int* hidx  = (const int*)d_in[8];
  const int* tidx  = (const int*)d_in[9];
  const int* hmask = (const int*)d_in[13];
  const int* tmask = (const int*)d_in[14];
  const float* dgW_t = (const float*)d_in[15];
  const float* dgb_t = (const float*)d_in[16];
  const float* gW_t  = (const float*)d_in[17];
  const float* gb_t  = (const float*)d_in[18];
  const float* cW_t  = (const float*)d_in[19];
  const float* cb_t  = (const float*)d_in[20];
  const float* dgW_h = (const float*)d_in[21];
  const float* dgb_h = (const float*)d_in[22];
  const float* gW_h  = (const float*)d_in[23];
  const float* gb_h  = (const float*)d_in[24];
  const float* cW_h  = (const float*)d_in[25];
  const float* cb_h  = (const float*)d_in[26];
  const float* dgW_f = (const float*)d_in[27];
  const float* dgb_f = (const float*)d_in[28];
  const float* gW_f  = (const float*)d_in[29];
  const float* gb_f  = (const float*)d_in[30];
  const float* cW_f  = (const float*)d_in[31];
  const float* cb_f  = (const float*)d_in[32];

  char* w = (char*)d_ws;
  size_t off = 0;
  auto alloc = [&](size_t bytes) -> char* {
    char* p = w + off;
    off += (bytes + 255) & ~(size_t)255;
    return p;
  };
  float* w2_all   = (float*)alloc((size_t)ETOT * 4);
  float* tri_all  = (float*)alloc((size_t)ETOT * 4);
  float* dinv_all = (float*)alloc((size_t)NTOT * 4);
  float* h_all    = (float*)alloc((size_t)HTOT * 4);
  float* xh_all   = (float*)alloc((size_t)HTOT * 4);
  int* invT       = (int*)alloc((size_t)EFULL * 4);
  int* invH       = (int*)alloc((size_t)EFULL * 4);
  (void)ws_size; (void)in_sizes; (void)n_in; (void)out_size;

  float* outp = (float*)d_out;

  k_init<<<(EFULL + 255) / 256, 256, 0, stream>>>(invT, invH);
  k_inv<<<(ETOP + EHUB + 255) / 256, 256, 0, stream>>>(tmask, hmask, invT, invH);
  k_ea_all<<<NB_T + NB_H + NB_F, 256, 0, stream>>>(ez, tmask, hmask,
      dgW_t, dgb_t, dgW_h, dgb_h, dgW_f, dgb_f, outp, w2_all);
  k_h_all<<<(HTOT + 255) / 256, 256, 0, stream>>>(nodez, wx, hub_wx, top_wx,
      hidx, tidx, gW_t, gW_h, gW_f, h_all);
  k_deg_all<<<NTOT, 64, 0, stream>>>(w2_all, dinv_all);
  k_xh_all<<<NTOT, 256, 0, stream>>>(w2_all, dinv_all, h_all, gb_t, gb_h, gb_f, xh_all);
  k_tri_all<<<(ETOT + 255) / 256, 256, 0, stream>>>(xh_all, tadj, hadj, adj, tri_all);
  k_final<<<(EFULL * 48 + 255) / 256, 256, 0, stream>>>(
      tri_all, invT, invH, cW_t, cb_t, cW_h, cb_h, cW_f, cb_f, outp);
}